// Round 9
// baseline (114.098 us; speedup 1.0000x reference)
//
#include <hip/hip_runtime.h>
#include <math.h>

#define B 64
#define T 4096
#define D 512
#define NCH 32            // 128-row chunks per batch row
#define CHT (T / NCH)     // 128 t per chunk
#define WSTRIP 32         // t-rows per wave
#define KB2 2             // rows per pipeline batch per wave (K+V planes)

typedef __attribute__((address_space(1))) const void global_cv;
typedef __attribute__((address_space(3))) void lds_v;

__device__ __forceinline__ float wave_sum64(float v) {
#pragma unroll
    for (int off = 32; off; off >>= 1)
        v += __shfl_xor(v, off, 64);
    return v;
}

// Async-stage one 2KB row into LDS: 2 x (64 lanes x 16B) global_load_lds.
// LDS dest is wave-uniform base (HW adds lane*16); global src is per-lane.
// +2 vmcnt per call per wave.
__device__ __forceinline__ void stage_row(const float* __restrict__ gsrc_row,
                                          float* lds_row, int lane) {
    __builtin_amdgcn_global_load_lds((global_cv*)(gsrc_row + lane * 4),
                                     (lds_v*)(lds_row), 16, 0, 0);
    __builtin_amdgcn_global_load_lds((global_cv*)(gsrc_row + 256 + lane * 4),
                                     (lds_v*)(lds_row + 256), 16, 0, 0);
}

// FUSED kernel: grid = B*32 (one 128-row chunk per block), 4 waves x 32-row
// strip. Per wave: compact live rows from mask, then DMA-pipeline {K row,
// V row} pairs through a 2-deep x 2-row LDS double buffer (counted vmcnt(8),
// no in-loop barriers). Per batch: LDS dots -> 2-row multiplexed butterfly ->
// g = exp(dot/sqrt(D)) -> attn store (unnormalized) -> acc += g * V (LDS).
// Masked rows never read. Denominator applied in finalize only.
__global__ __launch_bounds__(256) void fused_attn_kernel(const float* __restrict__ q,
                                                         const float* __restrict__ k,
                                                         const float* __restrict__ v,
                                                         const int* __restrict__ mask,
                                                         float* __restrict__ attn,
                                                         float* __restrict__ chunk_sums,
                                                         float* __restrict__ partial) {
    const float INV_SCALE = 0.04419417382415922f;  // 1/sqrt(512)

    __shared__ __align__(16) float kvbuf[2][4][KB2][2][D];  // 64 KB
    __shared__ int sm_list[4][WSTRIP + KB2];
    __shared__ float sred[4];
    __shared__ float sacc[4][D];                            // 8 KB

    int blk = blockIdx.x;
    int b = blk >> 5;
    int ch = blk & 31;
    int wave = threadIdx.x >> 6;
    int lane = threadIdx.x & 63;

    const float* qb = q + b * D;
    float4 qa = *(const float4*)(qb + lane * 4);
    float4 qc = *(const float4*)(qb + 256 + lane * 4);

    int t0 = ch * CHT + wave * WSTRIP;
    const float* kbase = k + ((size_t)b * T + t0) * D;
    const float* vbase = v + ((size_t)b * T + t0) * D;

    // 32-row mask bitmap + order-stable compaction (wave-local LDS list)
    int mv = (lane < WSTRIP) ? mask[b * T + t0 + lane] : 0;
    unsigned int mbits = (unsigned int)__ballot(mv != 0);
    int cnt = __popc(mbits);
    int row0 = (cnt > 0) ? (__ffs(mbits) - 1) : 0;
    if (lane < WSTRIP) {
        if (mv != 0) {
            int pre = __popc(mbits & ((1u << lane) - 1u));
            sm_list[wave][pre] = lane;
        } else {
            attn[(size_t)b * T + t0 + lane] = 0.0f;  // exact 0 for masked rows
        }
    }
    if (lane < KB2) sm_list[wave][cnt + lane] = row0;  // pad slots (L2 hit)

    int ngrp = (cnt + KB2 - 1) >> 1;

    // prologue: stage batches 0 and 1 (2 rows x {K,V} = 8 vmcnt each)
    if (ngrp > 0) {
#pragma unroll
        for (int r = 0; r < KB2; ++r) {
            int row = sm_list[wave][r];
            stage_row(kbase + (size_t)row * D, &kvbuf[0][wave][r][0][0], lane);
            stage_row(vbase + (size_t)row * D, &kvbuf[0][wave][r][1][0], lane);
        }
    }
    if (ngrp > 1) {
#pragma unroll
        for (int r = 0; r < KB2; ++r) {
            int row = sm_list[wave][KB2 + r];
            stage_row(kbase + (size_t)row * D, &kvbuf[1][wave][r][0][0], lane);
            stage_row(vbase + (size_t)row * D, &kvbuf[1][wave][r][1][0], lane);
        }
    }

    float gsum = 0.f;
    float4 accA = {0.f, 0.f, 0.f, 0.f}, accC = {0.f, 0.f, 0.f, 0.f};
    int rown = lane >> 5;   // which of the 2 rows this lane owns post-butterfly

#pragma unroll 1
    for (int i = 0; i < ngrp; ++i) {
        if (i + 1 < ngrp) asm volatile("s_waitcnt vmcnt(8)" ::: "memory");
        else              asm volatile("s_waitcnt vmcnt(0)" ::: "memory");

        float d2[KB2];
        float4 va[KB2], vc[KB2];
#pragma unroll
        for (int rr = 0; rr < KB2; ++rr) {
            float4 ka = *(const float4*)&kvbuf[i & 1][wave][rr][0][lane * 4];
            float4 kc = *(const float4*)&kvbuf[i & 1][wave][rr][0][256 + lane * 4];
            d2[rr] = ka.x * qa.x + ka.y * qa.y + ka.z * qa.z + ka.w * qa.w
                   + kc.x * qc.x + kc.y * qc.y + kc.z * qc.z + kc.w * qc.w;
            va[rr] = *(const float4*)&kvbuf[i & 1][wave][rr][1][lane * 4];
            vc[rr] = *(const float4*)&kvbuf[i & 1][wave][rr][1][256 + lane * 4];
        }

        // 2-row multiplexed butterfly: full dots in 6 shuffles
        bool b5 = (lane & 32) != 0;
        float u = b5 ? d2[1] : d2[0];
        float s = b5 ? d2[0] : d2[1];
        float h = u + __shfl_xor(s, 32, 64);
        h += __shfl_xor(h, 16, 64);
        h += __shfl_xor(h, 8, 64);
        h += __shfl_xor(h, 4, 64);
        h += __shfl_xor(h, 2, 64);
        h += __shfl_xor(h, 1, 64);
        // h = dot for row (i*2 + rown), replicated on 32 lanes

        int slot = i * KB2 + rown;
        float gval = 0.f;
        if (slot < cnt) {
            gval = __expf(h * INV_SCALE);
            if ((lane & 31) == 0)
                attn[(size_t)b * T + t0 + sm_list[wave][slot]] = gval;
        }
        gsum += gval;

        // all LDS reads of this buffer done before re-staging over it
        asm volatile("s_waitcnt lgkmcnt(0)" ::: "memory");
        if (i + 2 < ngrp) {
            int s0 = (i + 2) * KB2;
#pragma unroll
            for (int r = 0; r < KB2; ++r) {
                int row = sm_list[wave][s0 + r];
                stage_row(kbase + (size_t)row * D, &kvbuf[i & 1][wave][r][0][0], lane);
                stage_row(vbase + (size_t)row * D, &kvbuf[i & 1][wave][r][1][0], lane);
            }
        }

        float g0 = __shfl(gval, 0, 64);
        float g1 = __shfl(gval, 32, 64);
        accA.x += g0 * va[0].x; accA.y += g0 * va[0].y;
        accA.z += g0 * va[0].z; accA.w += g0 * va[0].w;
        accC.x += g0 * vc[0].x; accC.y += g0 * vc[0].y;
        accC.z += g0 * vc[0].z; accC.w += g0 * vc[0].w;
        accA.x += g1 * va[1].x; accA.y += g1 * va[1].y;
        accA.z += g1 * va[1].z; accA.w += g1 * va[1].w;
        accC.x += g1 * vc[1].x; accC.y += g1 * vc[1].y;
        accC.z += g1 * vc[1].z; accC.w += g1 * vc[1].w;
    }

    // combine 4 wave partials -> one partial row per block
    *(float4*)(&sacc[wave][lane * 4]) = accA;
    *(float4*)(&sacc[wave][256 + lane * 4]) = accC;
    // wave chunk-sum (each live row's g replicated on 32 lanes -> /32)
    float ws = wave_sum64(gsum) * 0.03125f;
    if (lane == 0) sred[wave] = ws;
    __syncthreads();

    int c0 = threadIdx.x * 2;
    float2 p;
    p.x = (sacc[0][c0]     + sacc[1][c0])     + (sacc[2][c0]     + sacc[3][c0]);
    p.y = (sacc[0][c0 + 1] + sacc[1][c0 + 1]) + (sacc[2][c0 + 1] + sacc[3][c0 + 1]);
    *(float2*)(partial + (size_t)(b * NCH + ch) * D + c0) = p;

    if (threadIdx.x == 0)
        chunk_sums[blk] = (sred[0] + sred[1]) + (sred[2] + sred[3]);
}

// Finalize: grid = B, block = 256. Rebuild denominator (identical fixed-order
// butterfly in every wave), reduce 32 partials -> ctx, normalize attn in place.
__global__ __launch_bounds__(256) void finalize_kernel(const float* __restrict__ partial,
                                                       const float* __restrict__ chunk_sums,
                                                       float* __restrict__ attn,
                                                       float* __restrict__ ctx) {
    int b = blockIdx.x;
    int tid = threadIdx.x;
    int lane = tid & 63;

    float cs = (lane < NCH) ? chunk_sums[b * NCH + lane] : 0.f;
    float denom = wave_sum64(cs);
    float inv = 1.0f / denom;

    // context: 512 cols, 2 per thread, fixed order over 32 chunks
    int c = tid * 2;
    float2 acc = {0.f, 0.f};
#pragma unroll 8
    for (int j = 0; j < NCH; ++j) {
        float2 p = *(const float2*)(partial + (size_t)(b * NCH + j) * D + c);
        acc.x += p.x;
        acc.y += p.y;
    }
    acc.x *= inv; acc.y *= inv;
    *(float2*)(ctx + (size_t)b * D + c) = acc;

    // attn: 4096 floats per b, 4 coalesced float4 per thread
#pragma unroll
    for (int j = 0; j < 4; ++j) {
        size_t idx = (size_t)b * T + (size_t)j * 1024 + tid * 4;
        float4 x = *(const float4*)(attn + idx);
        x.x *= inv; x.y *= inv; x.z *= inv; x.w *= inv;
        *(float4*)(attn + idx) = x;
    }
}

extern "C" void kernel_launch(void* const* d_in, const int* in_sizes, int n_in,
                              void* d_out, int out_size, void* d_ws, size_t ws_size,
                              hipStream_t stream) {
    const float* q    = (const float*)d_in[0];
    const float* k    = (const float*)d_in[1];
    const float* v    = (const float*)d_in[2];
    const int*   mask = (const int*)d_in[3];

    float* ctx  = (float*)d_out;            // [B, D]
    float* attn = (float*)d_out + B * D;    // [B, T]

    float* chunk_sums = (float*)d_ws;            // B*NCH floats = 8 KB
    float* partial    = (float*)d_ws + 8192;     // [B*NCH, D] = 4.2 MB

    fused_attn_kernel<<<B * NCH, 256, 0, stream>>>(q, k, v, mask, attn, chunk_sums, partial);
    finalize_kernel<<<B, 256, 0, stream>>>(partial, chunk_sums, attn, ctx);
}